// Round 22
// baseline (372.014 us; speedup 1.0000x reference)
//
#include <hip/hip_runtime.h>
#include <math.h>

#define E_ 65536
#define N_ 16384
#define M_ 262144

typedef unsigned short u16;
typedef unsigned long long u64;
typedef __attribute__((ext_vector_type(4))) float f32x4;
typedef __attribute__((ext_vector_type(8))) short bf16x8;
typedef __attribute__((ext_vector_type(4))) unsigned short u16x4;
typedef __attribute__((ext_vector_type(8))) unsigned short u16x8;
typedef __attribute__((ext_vector_type(2))) unsigned int u32x2;
typedef __attribute__((ext_vector_type(4))) float f4v;

__device__ __forceinline__ float b2f(u16 u) {
    union { unsigned u; float f; } x; x.u = ((unsigned)u) << 16; return x.f;
}
__device__ __forceinline__ u16 f2b(float f) {
    union { float f; unsigned u; } x; x.f = f;
    unsigned r = x.u + 0x7FFFu + ((x.u >> 16) & 1u);
    return (u16)(r >> 16);
}
// sigmoid-form GELU: x * sigmoid(1.702 x). ~1e-2 abs err, fine for bf16/fp8 pipeline.
__device__ __forceinline__ float gelu_f(float x) {
    return x * __builtin_amdgcn_rcpf(1.0f + __expf(-1.702f * x));
}

#define GLDS(gp, lp) __builtin_amdgcn_global_load_lds( \
    (const __attribute__((address_space(1))) void*)(gp), \
    (__attribute__((address_space(3))) void*)(lp), 16, 0, 0)

// counted-vmcnt pipeline primitives (T4): raw barrier (no vmcnt(0) drain) + counted waits.
#define CFENCE() asm volatile("" ::: "memory")
#define SBAR() do { CFENCE(); __builtin_amdgcn_s_barrier(); CFENCE(); } while (0)
#define VMCNT6() asm volatile("s_waitcnt vmcnt(6)" ::: "memory")
#define VMCNT0() asm volatile("s_waitcnt vmcnt(0)" ::: "memory")

// ---------------- zero int buffer ----------------
__global__ void ge_zero(int* __restrict__ p, int n) {
    int i = blockIdx.x * 256 + threadIdx.x;
    if (i < n) p[i] = 0;
}

// ---------------- weight convert/transpose/pack ----------------
// WqkvT8 [768][256] fp8 x16 (linear K).  W1T8 [1024][256] fp8 x16 (linear K).
// W2T8 [256][1024] fp8 x16, K-dim QUAD-PERMUTED to match ffh8 layout:
// stored k = base64 + lr*4 + ni  <->  true hidden = base64 + ni*16 + lr.
__global__ void ge_convw(const float* __restrict__ Wq, const float* __restrict__ Wk,
                         const float* __restrict__ Wv, const float* __restrict__ bq,
                         const float* __restrict__ bk, const float* __restrict__ bv,
                         const float* __restrict__ Wo, const float* __restrict__ W1,
                         const float* __restrict__ W2, const float* __restrict__ We2n,
                         unsigned char* __restrict__ WqkvT8, float* __restrict__ bqkv,
                         u16* __restrict__ WoT, unsigned char* __restrict__ W1T8,
                         unsigned char* __restrict__ W2T8, u16* __restrict__ We2nT) {
    long i = (long)blockIdx.x * 256 + threadIdx.x;
    if (i < 196608) {  // WqkvT8 [768][256] fp8, x16
        int n = (int)(i >> 8), k = (int)(i & 255);
        const float* W = (n < 256) ? Wq : ((n < 512) ? Wk : Wv);
        int nn = n & 255;
        unsigned pk = __builtin_amdgcn_cvt_pk_fp8_f32(W[k * 256 + nn] * 16.0f, 0.0f, 0u, false);
        WqkvT8[i] = (unsigned char)(pk & 0xFFu);
        return;
    }
    i -= 196608;
    if (i < 768) { bqkv[i] = (i < 256) ? bq[i] : ((i < 512) ? bk[i - 256] : bv[i - 512]); return; }
    i -= 768;
    if (i < 65536) { int n = (int)(i >> 8), k = (int)(i & 255); WoT[i] = f2b(Wo[k * 256 + n]); return; }
    i -= 65536;
    if (i < 262144) {  // W1T8 [1024][256] fp8, x16 scale, linear K
        int n = (int)(i >> 8), k = (int)(i & 255);
        unsigned pk = __builtin_amdgcn_cvt_pk_fp8_f32(W1[k * 1024 + n] * 16.0f, 0.0f, 0u, false);
        W1T8[i] = (unsigned char)(pk & 0xFFu);
        return;
    }
    i -= 262144;
    if (i < 262144) {  // W2T8 [256][1024] fp8, quad-permuted K, x16 scale
        int n = (int)(i / 1024), k = (int)(i % 1024);
        int k64 = k & 63, base = k - k64;
        int old_k = base + (k64 & 3) * 16 + (k64 >> 2);
        unsigned pk = __builtin_amdgcn_cvt_pk_fp8_f32(W2[old_k * 256 + n] * 16.0f, 0.0f, 0u, false);
        W2T8[i] = (unsigned char)(pk & 0xFFu);
        return;
    }
    i -= 262144;
    if (i < 65536) { int n = (int)(i >> 8), k = (int)(i & 255); We2nT[i] = f2b(We2n[k * 256 + n]); return; }
}

// ---------------- LayerNorm row (D=256); IN: 0=f32,1=bf16; OUT: 0=bf16,1=fp8 x8 ----------------
template <int BF16IN, int FP8OUT>
__global__ __launch_bounds__(256) void ge_ln(const void* __restrict__ in,
                                             const float* __restrict__ s,
                                             const float* __restrict__ b,
                                             void* __restrict__ out) {
    int tid = threadIdx.x, l = tid & 63, w = tid >> 6;
    long r = (long)blockIdx.x * 4 + w;
    float x0, x1, x2, x3;
    if constexpr (BF16IN) {
        u16x4 xv = *(const u16x4*)&((const u16*)in)[r * 256 + 4 * l];
        x0 = b2f(xv[0]); x1 = b2f(xv[1]); x2 = b2f(xv[2]); x3 = b2f(xv[3]);
    } else {
        f4v x = *(const f4v*)&((const float*)in)[r * 256 + 4 * l];
        x0 = x[0]; x1 = x[1]; x2 = x[2]; x3 = x[3];
    }
    float sum = x0 + x1 + x2 + x3;
#pragma unroll
    for (int off = 1; off < 64; off <<= 1) sum += __shfl_xor(sum, off);
    float mean = sum * (1.0f / 256.0f);
    float d0 = x0 - mean, d1 = x1 - mean, d2 = x2 - mean, d3 = x3 - mean;
    float ss = d0 * d0 + d1 * d1 + d2 * d2 + d3 * d3;
#pragma unroll
    for (int off = 1; off < 64; off <<= 1) ss += __shfl_xor(ss, off);
    float rs = rsqrtf(ss * (1.0f / 256.0f) + 1e-5f);
    float y0 = d0 * rs * s[4 * l + 0] + b[4 * l + 0];
    float y1 = d1 * rs * s[4 * l + 1] + b[4 * l + 1];
    float y2 = d2 * rs * s[4 * l + 2] + b[4 * l + 2];
    float y3 = d3 * rs * s[4 * l + 3] + b[4 * l + 3];
    if constexpr (FP8OUT) {
        unsigned pk = __builtin_amdgcn_cvt_pk_fp8_f32(y0 * 8.0f, y1 * 8.0f, 0u, false);
        pk = __builtin_amdgcn_cvt_pk_fp8_f32(y2 * 8.0f, y3 * 8.0f, pk, true);
        *(unsigned*)&((unsigned char*)out)[r * 256 + 4 * l] = pk;
    } else {
        u16x4 o;
        o[0] = f2b(y0); o[1] = f2b(y1); o[2] = f2b(y2); o[3] = f2b(y3);
        *(u16x4*)&((u16*)out)[r * 256 + 4 * l] = o;
    }
}

// ---------------- CSR build: count, hierarchical scan, fill ----------------
__global__ void ge_count(const int* __restrict__ idx, int* __restrict__ cnt, int n) {
    int i = blockIdx.x * 256 + threadIdx.x;
    if (i < n) atomicAdd(&cnt[idx[i]], 1);
}

__global__ __launch_bounds__(256) void ge_bsum(const int* __restrict__ cnt,
                                               int* __restrict__ bsum, int n) {
    int i = blockIdx.x * 256 + threadIdx.x;
    int v = (i < n) ? cnt[i] : 0;
#pragma unroll
    for (int off = 1; off < 64; off <<= 1) v += __shfl_xor(v, off);
    __shared__ int ws_[4];
    int l = threadIdx.x & 63, w = threadIdx.x >> 6;
    if (l == 0) ws_[w] = v;
    __syncthreads();
    if (threadIdx.x == 0) bsum[blockIdx.x] = ws_[0] + ws_[1] + ws_[2] + ws_[3];
}

__global__ __launch_bounds__(256) void ge_bscan(int* __restrict__ bsum, int nb) {
    __shared__ int lds[256];
    int tid = threadIdx.x;
    int v = (tid < nb) ? bsum[tid] : 0;
    lds[tid] = v;
    __syncthreads();
#pragma unroll
    for (int off = 1; off < 256; off <<= 1) {
        int t = (tid >= off) ? lds[tid - off] : 0;
        __syncthreads();
        lds[tid] += t;
        __syncthreads();
    }
    if (tid < nb) bsum[tid] = lds[tid] - v;  // exclusive
}

__global__ __launch_bounds__(256) void ge_cscan(const int* __restrict__ cnt,
                                                const int* __restrict__ bsum,
                                                int* __restrict__ rowStart,
                                                int* __restrict__ cursor,
                                                float* __restrict__ ldeg, int n) {
    __shared__ int lds[256];
    int tid = threadIdx.x;
    int i = blockIdx.x * 256 + tid;
    int c = (i < n) ? cnt[i] : 0;
    lds[tid] = c;
    __syncthreads();
#pragma unroll
    for (int off = 1; off < 256; off <<= 1) {
        int t = (tid >= off) ? lds[tid - off] : 0;
        __syncthreads();
        lds[tid] += t;
        __syncthreads();
    }
    if (i < n) {
        int ex = bsum[blockIdx.x] + lds[tid] - c;
        rowStart[i] = ex;
        cursor[i] = ex;
        if (ldeg) ldeg[i] = log1pf((float)c);
        if (i == n - 1) rowStart[n] = ex + c;
    }
}

__global__ void ge_fill(const int* __restrict__ idx, int* __restrict__ cursor,
                        int* __restrict__ csr, int n, int modE) {
    int i = blockIdx.x * 256 + threadIdx.x;
    if (i < n) {
        int slot = atomicAdd(&cursor[idx[i]], 1);
        csr[slot] = (modE && i >= modE) ? (i - modE) : i;
    }
}

__global__ void ge_fill_attn(const int* __restrict__ dst, const int* __restrict__ src,
                             const float* __restrict__ eeb, int* __restrict__ cursor,
                             int* __restrict__ csrSrc, float* __restrict__ biasCsr, int n) {
    int i = blockIdx.x * 256 + threadIdx.x;
    if (i < n) {
        int slot = atomicAdd(&cursor[dst[i]], 1);
        csrSrc[slot] = src[i];
        f4v b0 = *(const f4v*)&eeb[(size_t)i * 8];
        f4v b1 = *(const f4v*)&eeb[(size_t)i * 8 + 4];
        *(f4v*)&biasCsr[(size_t)slot * 8] = b0;
        *(f4v*)&biasCsr[(size_t)slot * 8 + 4] = b1;
    }
}

// ---------------- GEMM (bf16): 128x128 tile, grouped block order ----------------
// EPI 1: out bf16 = C + bias + res(f32)          (Wo + residual -> h1 bf16)
// EPI 4: out f32  = C + bias + res(f32)          (We2n + x)
template <int EPI>
__global__ __launch_bounds__(256) void ge_gemm(
    const u16* __restrict__ A, const u16* __restrict__ Bt, int K, int nxt,
    const float* __restrict__ bias, const float* __restrict__ res,
    float* __restrict__ outF, u16* __restrict__ outB, int ldOut) {
    __shared__ __align__(16) char smem[32768];
    const int tid = threadIdx.x;
    const int l = tid & 63, w = tid >> 6;
    const int ny = gridDim.x / nxt;
    const int gsz = 64 * ny;
    const int bid = blockIdx.x;
    const int xt = (bid / gsz) * 64 + (bid % gsz) % 64;
    const int yt = (bid % gsz) / 64;
    const int rowBase = xt * 128, colBase = yt * 128;
    const int ar = tid >> 2, aq = tid & 3;
    const int aqs = aq ^ ((ar >> 1) & 3);  // source-side chunk swizzle, phase-uniform
    const u16* Ag = A + (size_t)(rowBase + ar) * K + aqs * 8;
    const u16* Bg = Bt + (size_t)(colBase + ar) * K + aqs * 8;
    const size_t row64 = (size_t)64 * K;

    f32x4 acc[4][4] = {};
    const int lr = l & 15;
    const int ks2 = (((l >> 4) ^ ((l >> 1) & 3)) << 3);  // read-side, f(row)=(row>>1)&3
    const int wr = (w >> 1) * 64, wc = (w & 1) * 64;
    const int nt = K >> 5;

    auto STAGE = [&](int b, int t) {
        const int kk = t * 32;
        char* dA = smem + b * 8192 + w * 1024;
        char* dB = smem + 16384 + b * 8192 + w * 1024;
        GLDS(Ag + kk, dA);
        GLDS(Ag + kk + row64, dA + 4096);
        GLDS(Bg + kk, dB);
        GLDS(Bg + kk + row64, dB + 4096);
    };

    STAGE(0, 0);
    __syncthreads();
    int cur = 0;
    for (int t = 0; t < nt; ++t) {
        if (t + 1 < nt) STAGE(cur ^ 1, t + 1);
        const u16* bufA = (const u16*)(smem + cur * 8192);
        const u16* bufB = (const u16*)(smem + 16384 + cur * 8192);
        bf16x8 af[4], bfr[4];
#pragma unroll
        for (int mi = 0; mi < 4; mi++) af[mi] = *(const bf16x8*)&bufA[(wr + mi * 16 + lr) * 32 + ks2];
#pragma unroll
        for (int ni = 0; ni < 4; ni++) bfr[ni] = *(const bf16x8*)&bufB[(wc + ni * 16 + lr) * 32 + ks2];
#pragma unroll
        for (int mi = 0; mi < 4; mi++)
#pragma unroll
            for (int ni = 0; ni < 4; ni++)
                acc[mi][ni] = __builtin_amdgcn_mfma_f32_16x16x32_bf16(af[mi], bfr[ni], acc[mi][ni], 0, 0, 0);
        if (t + 1 < nt) {
            __syncthreads();
            cur ^= 1;
        }
    }

    const int r0 = (l >> 4) * 4;
#pragma unroll
    for (int mi = 0; mi < 4; mi++) {
#pragma unroll
        for (int ni = 0; ni < 4; ni++) {
#pragma unroll
            for (int r = 0; r < 4; r++) {
                int grow = rowBase + wr + mi * 16 + r0 + r;
                int gcol = colBase + wc + ni * 16 + lr;
                float c = acc[mi][ni][r];
                if constexpr (EPI == 1) {
                    outB[(size_t)grow * ldOut + gcol] =
                        f2b(c + bias[gcol] + res[(size_t)grow * 256 + gcol]);
                } else {
                    outF[(size_t)grow * ldOut + gcol] =
                        c + bias[gcol] + res[(size_t)grow * 256 + gcol];
                }
            }
        }
    }
}

// ---------------- QKV GEMM, fp8 x fp8, 128x128 tile, K=256 (nt=4) ----------------
// A = en8 [E][256] fp8 (LN1 x8), Bt = WqkvT8 [768][256] fp8 (x16). acc/128 + bias.
// Epilogue: LDS transpose -> q [E][256] bf16 + kv8 [E][512 bytes] fp8 x8 interleaved
// (block d: bytes 8d..8d+3 = K[4d..4d+3]*8, bytes 8d+4..8d+7 = V[4d..4d+3]*8).
__global__ __launch_bounds__(256) void ge_gemm5f8(
    const unsigned char* __restrict__ A, const unsigned char* __restrict__ Bt, int nxt,
    const float* __restrict__ bias, u16* __restrict__ outB, unsigned char* __restrict__ outKV8) {
    __shared__ __align__(16) char smem[32768];
    const int tid = threadIdx.x;
    const int l = tid & 63, w = tid >> 6;
    const int ny = gridDim.x / nxt;
    const int gsz = 64 * ny;
    const int bid = blockIdx.x;
    const int xt = (bid / gsz) * 64 + (bid % gsz) % 64;
    const int yt = (bid % gsz) / 64;
    const int rowBase = xt * 128, colBase = yt * 128;
    const int ar = tid >> 2, aq = tid & 3;
    const int aqs = aq ^ ((ar >> 1) & 3);
    const unsigned char* Ag = A + (size_t)(rowBase + ar) * 256 + aqs * 16;
    const unsigned char* Bg = Bt + (size_t)(colBase + ar) * 256 + aqs * 16;
    const size_t row64 = (size_t)64 * 256;

    f32x4 acc[4][4] = {};
    const int lr = l & 15, q = l >> 4;
    const int fx = (l >> 1) & 3;
    const int wr = (w >> 1) * 64, wc = (w & 1) * 64;

    auto STAGE = [&](int b, int t) {
        const size_t kk = (size_t)t * 64;
        char* dA = smem + b * 8192 + w * 1024;
        char* dB = smem + 16384 + b * 8192 + w * 1024;
        GLDS(Ag + kk, dA);
        GLDS(Ag + kk + row64, dA + 4096);
        GLDS(Bg + kk, dB);
        GLDS(Bg + kk + row64, dB + 4096);
    };

    STAGE(0, 0);
    __syncthreads();
    int cur = 0;
    for (int t = 0; t < 4; ++t) {
        if (t + 1 < 4) STAGE(cur ^ 1, t + 1);
        const unsigned char* bufA = (const unsigned char*)(smem + cur * 8192);
        const unsigned char* bufB = (const unsigned char*)(smem + 16384 + cur * 8192);
#pragma unroll
        for (int s = 0; s < 2; ++s) {
            long long af[4], bf[4];
#pragma unroll
            for (int mi = 0; mi < 4; mi++) {
                int row = wr + mi * 16 + lr;
                af[mi] = *(const long long*)&bufA[row * 64 + ((2 * s + (q >> 1)) ^ fx) * 16 + (q & 1) * 8];
            }
#pragma unroll
            for (int ni = 0; ni < 4; ni++) {
                int col = wc + ni * 16 + lr;
                bf[ni] = *(const long long*)&bufB[col * 64 + ((2 * s + (q >> 1)) ^ fx) * 16 + (q & 1) * 8];
            }
#pragma unroll
            for (int mi = 0; mi < 4; mi++)
#pragma unroll
                for (int ni = 0; ni < 4; ni++)
                    acc[mi][ni] = __builtin_amdgcn_mfma_f32_16x16x32_fp8_fp8(af[mi], bf[ni], acc[mi][ni], 0, 0, 0);
        }
        if (t + 1 < 4) {
            __syncthreads();
            cur ^= 1;
        }
    }

    const int r0 = q * 4;
    // LDS transpose epilogue: acc/128 + bias -> bf16 staging, then q bf16 / kv fp8 stores
    __syncthreads();
    u16* ep = (u16*)smem;  // [128][128]
#pragma unroll
    for (int mi = 0; mi < 4; mi++) {
#pragma unroll
        for (int ni = 0; ni < 4; ni++) {
#pragma unroll
            for (int r = 0; r < 4; r++) {
                int rl = wr + mi * 16 + r0 + r;
                int cl = wc + ni * 16 + lr;
                float c = acc[mi][ni][r] * 0.0078125f + bias[colBase + cl];
                ep[rl * 128 + (cl ^ (((rl >> 2) & 3) << 4))] = f2b(c);
            }
        }
    }
    __syncthreads();
#pragma unroll
    for (int j = 0; j < 8; j++) {
        int lin = tid + j * 256;
        int row = lin >> 4, ch = lin & 15;
        int grow = rowBase + row;
        bf16x8 v = *(const bf16x8*)&ep[row * 128 + ((ch * 8) ^ (((row >> 2) & 3) << 4))];
        int gcol0 = colBase + ch * 8;
        if (gcol0 < 256) {
            *(bf16x8*)&outB[(size_t)grow * 256 + gcol0] = v;
        } else {
            float f0 = b2f((u16)v[0]) * 8.0f, f1 = b2f((u16)v[1]) * 8.0f;
            float f2 = b2f((u16)v[2]) * 8.0f, f3 = b2f((u16)v[3]) * 8.0f;
            float f4 = b2f((u16)v[4]) * 8.0f, f5 = b2f((u16)v[5]) * 8.0f;
            float f6 = b2f((u16)v[6]) * 8.0f, f7 = b2f((u16)v[7]) * 8.0f;
            unsigned pk0 = __builtin_amdgcn_cvt_pk_fp8_f32(f0, f1, 0u, false);
            pk0 = __builtin_amdgcn_cvt_pk_fp8_f32(f2, f3, pk0, true);
            unsigned pk1 = __builtin_amdgcn_cvt_pk_fp8_f32(f4, f5, 0u, false);
            pk1 = __builtin_amdgcn_cvt_pk_fp8_f32(f6, f7, pk1, true);
            if (gcol0 < 512) {
                int d0 = (gcol0 - 256) >> 2;  // even
                size_t base = (size_t)grow * 512 + 8 * d0;
                *(unsigned*)&outKV8[base] = pk0;
                *(unsigned*)&outKV8[base + 8] = pk1;
            } else {
                int d0 = (gcol0 - 512) >> 2;  // even
                size_t base = (size_t)grow * 512 + 8 * d0 + 4;
                *(unsigned*)&outKV8[base] = pk0;
                *(unsigned*)&outKV8[base + 8] = pk1;
            }
        }
    }
}

// ---------------- FFN-up GEMM, fp8 x fp8, 128x128 tile, K=256 (nt=4, R16-proven) ------
__global__ __launch_bounds__(256) void ge_gemm2f8(
    const unsigned char* __restrict__ A, const unsigned char* __restrict__ Bt, int nxt,
    const float* __restrict__ bias, unsigned char* __restrict__ out8) {
    __shared__ __align__(16) char smem[32768];
    const int tid = threadIdx.x;
    const int l = tid & 63, w = tid >> 6;
    const int ny = gridDim.x / nxt;
    const int gsz = 64 * ny;
    const int bid = blockIdx.x;
    const int xt = (bid / gsz) * 64 + (bid % gsz) % 64;
    const int yt = (bid % gsz) / 64;
    const int rowBase = xt * 128, colBase = yt * 128;
    const int ar = tid >> 2, aq = tid & 3;
    const int aqs = aq ^ ((ar >> 1) & 3);
    const unsigned char* Ag = A + (size_t)(rowBase + ar) * 256 + aqs * 16;
    const unsigned char* Bg = Bt + (size_t)(colBase + ar) * 256 + aqs * 16;
    const size_t row64 = (size_t)64 * 256;

    f32x4 acc[4][4] = {};
    const int lr = l & 15, q = l >> 4;
    const int fx = (l >> 1) & 3;
    const int wr = (w >> 1) * 64, wc = (w & 1) * 64;

    auto STAGE = [&](int b, int t) {
        const size_t kk = (size_t)t * 64;
        char* dA = smem + b * 8192 + w * 1024;
        char* dB = smem + 16384 + b * 8192 + w * 1024;
        GLDS(Ag + kk, dA);
        GLDS(Ag + kk + row64, dA + 4096);
        GLDS(Bg + kk, dB);
        GLDS(Bg + kk + row64, dB + 4096);
    };

    STAGE(0, 0);
    __syncthreads();
    int cur = 0;
    for (int t = 0; t < 4; ++t) {
        if (t + 1 < 4) STAGE(cur ^ 1, t + 1);
        const unsigned char* bufA = (const unsigned char*)(smem + cur * 8192);
        const unsigned char* bufB = (const unsigned char*)(smem + 16384 + cur * 8192);
#pragma unroll
        for (int s = 0; s < 2; ++s) {
            long long af[4], bf[4];
#pragma unroll
            for (int mi = 0; mi < 4; mi++) {
                int row = wr + mi * 16 + lr;
                af[mi] = *(const long long*)&bufA[row * 64 + ((2 * s + (q >> 1)) ^ fx) * 16 + (q & 1) * 8];
            }
#pragma unroll
            for (int ni = 0; ni < 4; ni++) {
                int col = wc + ni * 16 + lr;
                bf[ni] = *(const long long*)&bufB[col * 64 + ((2 * s + (q >> 1)) ^ fx) * 16 + (q & 1) * 8];
            }
#pragma unroll
            for (int mi = 0; mi < 4; mi++)
#pragma unroll
                for (int ni = 0; ni < 4; ni++)
                    acc[mi][ni] = __builtin_amdgcn_mfma_f32_16x16x32_fp8_fp8(af[mi], bf[ni], acc[mi][ni], 0, 0, 0);
        }
        if (t + 1 < 4) {
            __syncthreads();
            cur ^= 1;
        }
    }

    const int r0 = q * 4;
    float bv[4];
#pragma unroll
    for (int ni = 0; ni < 4; ni++) bv[ni] = bias[colBase + wc + ni * 16 + lr];
#pragma unroll
    for (int mi = 0; mi < 4; mi++) {
#pragma unroll
        for (int r = 0; r < 4; r++) {
            int grow = rowBase + wr + mi * 16 + r0 + r;
            float v0 = gelu_f(acc[mi][0][r] * 0.0078125f + bv[0]) * 8.0f;
            float v1 = gelu_f(acc[mi][1][r] * 0.0078125f + bv[1]) * 8.0f;
            float v2 = gelu_f(acc[mi][2][r] * 0.0078125f + bv[2]) * 8.0f;
            float v3 = gelu_f(acc[mi][3][r] * 0.0078125f + bv[3]) * 8.0f;
            unsigned pk = __builtin_amdgcn_cvt_pk_fp8_f32(v0, v1, 0u, false);
            pk = __builtin_amdgcn_cvt_pk_fp8_f32(v2, v3, pk, true);
            *(unsigned*)&out8[(size_t)grow * 1024 + colBase + wc + lr * 4] = pk;
        }
    }
}

// ---------------- FFN-down GEMM, fp8 x fp8, 256x128 tile, counted-vmcnt pipeline ------
// K-loop unchanged (R21). NEW: chunked LDS-transpose epilogue — per mi-fragment, scatter
// acc to a swizzled 32x128 f32 lbuf, then each thread owns 16 CONSECUTIVE output cols of
// one row: resB as 2x16B loads, dcoef/bias hoisted f4v, 1 ldeg/chunk, stores 4x f4v.
// Arithmetic per element identical to R21 (same op order), only access pattern changes.
__global__ __launch_bounds__(256) void ge_gemm3f8(
    const unsigned char* __restrict__ A, const unsigned char* __restrict__ Bt, int nxt,
    const float* __restrict__ bias, const u16* __restrict__ resB,
    const float* __restrict__ ldeg, const float* __restrict__ dcoef,
    float* __restrict__ outF) {
    __shared__ __align__(16) char smem[49152];
    const int tid = threadIdx.x;
    const int l = tid & 63, w = tid >> 6;
    const int ny = gridDim.x / nxt;
    const int gsz = 64 * ny;
    const int bid = blockIdx.x;
    const int xt = (bid / gsz) * 64 + (bid % gsz) % 64;
    const int yt = (bid % gsz) / 64;
    const int rowBase = xt * 256, colBase = yt * 128;
    const int ar = tid >> 2, aq = tid & 3;
    const int aqs = aq ^ ((ar >> 1) & 3);
    const unsigned char* Ag = A + (size_t)(rowBase + ar) * 1024 + aqs * 16;
    const unsigned char* Bg = Bt + (size_t)(colBase + ar) * 1024 + aqs * 16;
    const size_t row64 = (size_t)64 * 1024;

    f32x4 acc[8][4] = {};
    const int lr = l & 15, q = l >> 4;
    const int fx = (l >> 1) & 3;
    const int wr = (w >> 1) * 128, wc = (w & 1) * 64;

    auto STAGE = [&](int b, int t) {
        const size_t kk = (size_t)t * 64;
        char* dA = smem + b * 16384 + w * 1024;
        char* dB = smem + 32768 + b * 8192 + w * 1024;
        GLDS(Ag + kk, dA);
        GLDS(Ag + kk + row64, dA + 4096);
        GLDS(Ag + kk + 2 * row64, dA + 8192);
        GLDS(Ag + kk + 3 * row64, dA + 12288);
        GLDS(Bg + kk, dB);
        GLDS(Bg + kk + row64, dB + 4096);
    };

    STAGE(0, 0);
    STAGE(1, 1);  // 12 loads in flight
    int cur = 0;
    for (int t = 0; t < 16; ++t) {
        if (t < 15) { VMCNT6(); } else { VMCNT0(); }  // tile t's 6 oldest loads landed
        SBAR();                                       // tile t visible to all waves
        const unsigned char* bufA = (const unsigned char*)(smem + cur * 16384);
        const unsigned char* bufB = (const unsigned char*)(smem + 32768 + cur * 8192);
#pragma unroll
        for (int s = 0; s < 2; ++s) {
            long long af[8], bf[4];
#pragma unroll
            for (int mi = 0; mi < 8; mi++) {
                int row = wr + mi * 16 + lr;
                af[mi] = *(const long long*)&bufA[row * 64 + ((2 * s + (q >> 1)) ^ fx) * 16 + (q & 1) * 8];
            }
#pragma unroll
            for (int ni = 0; ni < 4; ni++) {
                int col = wc + ni * 16 + lr;
                bf[ni] = *(const long long*)&bufB[col * 64 + ((2 * s + (q >> 1)) ^ fx) * 16 + (q & 1) * 8];
            }
#pragma unroll
            for (int mi = 0; mi < 8; mi++)
#pragma unroll
                for (int ni = 0; ni < 4; ni++)
                    acc[mi][ni] = __builtin_amdgcn_mfma_f32_16x16x32_fp8_fp8(af[mi], bf[ni], acc[mi][ni], 0, 0, 0);
        }
        SBAR();                                       // all waves done reading buf[cur]
        if (t + 2 < 16) STAGE(cur, t + 2);            // restage freed buffer, loads stay in flight
        cur ^= 1;
    }
    // vmcnt==0 here (t=15 did VMCNT0; no stages after t=13). LDS free for epilogue.

    // ---- chunked LDS-transpose epilogue ----
    float* lbuf = (float*)smem;  // [32][128] f32 = 16KB
    const int lrow_r = tid >> 3;        // 0..31
    const int bcol = tid & 7;           // 16-col block index
    const int physb = bcol ^ ((lrow_r >> 2) & 3);
    const int gcol0 = colBase + bcol * 16;
    f4v biasv[4], dcv[8];
#pragma unroll
    for (int j = 0; j < 4; j++) biasv[j] = *(const f4v*)&bias[gcol0 + j * 4];
#pragma unroll
    for (int i2 = 0; i2 < 8; i2++) dcv[i2] = *(const f4v*)&dcoef[2 * gcol0 + 4 * i2];

#pragma unroll
    for (int mi = 0; mi < 8; mi++) {
        __syncthreads();  // previous chunk's reads complete before overwrite
        // scatter: lrow = (w>>1)*16 + q*4 + r, lcol = wc + ni*16 + lr, XOR key = (lrow>>2)&3 = q
#pragma unroll
        for (int ni = 0; ni < 4; ni++) {
#pragma unroll
            for (int r = 0; r < 4; r++) {
                int lrow = (w >> 1) * 16 + q * 4 + r;
                int lcol = wc + ni * 16 + lr;
                lbuf[lrow * 128 + (lcol ^ (q << 4))] = acc[mi][ni][r];
            }
        }
        __syncthreads();
        // gather: thread owns row lrow_r, cols [bcol*16, +16)
        int grow_r = rowBase + (lrow_r >> 4) * 128 + mi * 16 + (lrow_r & 15);
        float ldv = ldeg[grow_r];
        bf16x8 ra = *(const bf16x8*)&resB[(size_t)grow_r * 256 + gcol0];
        bf16x8 rb = *(const bf16x8*)&resB[(size_t)grow_r * 256 + gcol0 + 8];
#pragma unroll
        for (int j = 0; j < 4; j++) {
            f4v lv = *(const f4v*)&lbuf[lrow_r * 128 + physb * 16 + j * 4];
            f4v o;
#pragma unroll
            for (int k = 0; k < 4; k++) {
                int c = j * 4 + k;
                float res = b2f((u16)(c < 8 ? ra[c] : rb[c - 8]));
                float t2 = lv[k] * 0.0078125f + biasv[j][k] + res;
                float c0 = dcv[c >> 1][(c & 1) * 2];
                float c1 = dcv[c >> 1][(c & 1) * 2 + 1];
                o[k] = t2 * (c0 + ldv * c1);
            }
            *(f4v*)&outF[(size_t)grow_r * 256 + gcol0 + j * 4] = o;
        }
    }
}

// ---------------- per-dst-segment attention: fp8 KV gathers, single-pass softmax ------
// kv8 row: block d: bytes 8d..8d+3 = K[4d..4d+3]*8 fp8, bytes 8d+4..8d+7 = V[4d..4d+3]*8.
// Lane l reads 8 bytes; scales folded: logit = p*(scale/8)+bias, out = a*(1/8)/sum.
__global__ __launch_bounds__(256) void ge_attn(const u16* __restrict__ qb,
                                               const unsigned char* __restrict__ kv8,
                                               const float* __restrict__ biasCsr,
                                               const int* __restrict__ csrSrc,
                                               const int* __restrict__ rowStart,
                                               u16* __restrict__ agg) {
    int tid = threadIdx.x, l = tid & 63, w = tid >> 6;
    int e = blockIdx.x * 4 + w;
    int g = l >> 3;
    const float scale8 = 0.022097086912079608f;  // 32^-0.5 / 8
    u16x4 qv = *(const u16x4*)&qb[(size_t)e * 256 + 4 * l];
    float q0 = b2f(qv[0]), q1 = b2f(qv[1]), q2 = b2f(qv[2]), q3 = b2f(qv[3]);
    int s0 = rowStart[e], s1 = rowStart[e + 1];

    float sum = 0.0f, a0 = 0.0f, a1 = 0.0f, a2 = 0.0f, a3 = 0.0f;
    if (s0 < s1) {
        int sc = csrSrc[s0];
        u64 kvc = *(const u64*)&kv8[(size_t)sc * 512 + 8 * l];
        float bc = biasCsr[(size_t)s0 * 8 + g];
        for (int i = s0; i < s1; i++) {
            int inx = (i + 1 < s1) ? (i + 1) : i;
            int sn = csrSrc[inx];
            u64 kvn = *(const u64*)&kv8[(size_t)sn * 512 + 8 * l];
            float bn = biasCsr[(size_t)inx * 8 + g];
            unsigned klo = (unsigned)kvc, vhi = (unsigned)(kvc >> 32);
            float p = q0 * __builtin_amdgcn_cvt_f32_fp8(klo, 0) +
                      q1 * __builtin_amdgcn_cvt_f32_fp8(klo, 1) +
                      q2 * __builtin_amdgcn_cvt_f32_fp8(klo, 2) +
                      q3 * __builtin_amdgcn_cvt_f32_fp8(klo, 3);
            p += __shfl_xor(p, 1);
            p += __shfl_xor(p, 2);
            p += __shfl_xor(p, 4);
            float ex = __expf(p * scale8 + bc);  // logits bounded, no max pass needed
            sum += ex;
            a0 += ex * __builtin_amdgcn_cvt_f32_fp8(vhi, 0);
            a1 += ex * __builtin_amdgcn_cvt_f32_fp8(vhi, 1);
            a2 += ex * __builtin_amdgcn_cvt_f32_fp8(vhi, 2);
            a3 += ex * __builtin_amdgcn_cvt_f32_fp8(vhi, 3);
            kvc = kvn;
            bc = bn;
        }
    }
    float inv = 0.125f / (sum + 1e-16f);
    u16x4 o;
    o[0] = f2b(a0 * inv);
    o[1] = f2b(a1 * inv);
    o[2] = f2b(a2 * inv);
    o[3] = f2b(a3 * inv);
    *(u16x4*)&agg[(size_t)e * 256 + 4 * l] = o;
}

// ---------------- node aggregation: sum edge_out rows per node -> bf16 ----------------
__global__ __launch_bounds__(256) void ge_nodeagg(const float* __restrict__ edge_out,
                                                  const int* __restrict__ rowStart,
                                                  const int* __restrict__ csr,
                                                  u16* __restrict__ nmsg) {
    int tid = threadIdx.x, l = tid & 63, w = tid >> 6;
    int n = blockIdx.x * 4 + w;
    int s0 = rowStart[n], s1 = rowStart[n + 1];
    float a0 = 0.0f, a1 = 0.0f, a2 = 0.0f, a3 = 0.0f;
    for (int i = s0; i < s1; i++) {
        int e = csr[i];
        f4v v = *(const f4v*)&edge_out[(size_t)e * 256 + 4 * l];
        a0 += v[0]; a1 += v[1]; a2 += v[2]; a3 += v[3];
    }
    u16x4 o;
    o[0] = f2b(a0); o[1] = f2b(a1); o[2] = f2b(a2); o[3] = f2b(a3);
    *(u16x4*)&nmsg[(size_t)n * 256 + 4 * l] = o;
}

extern "C" void kernel_launch(void* const* d_in, const int* in_sizes, int n_in,
                              void* d_out, int out_size, void* d_ws, size_t ws_size,
                              hipStream_t stream) {
    (void)in_sizes; (void)n_in; (void)out_size; (void)ws_size;
    const float* edge_attr = (const float*)d_in[0];
    const float* x = (const float*)d_in[1];
    const int* src_e = (const int*)d_in[2];
    const int* dst_e = (const int*)d_in[3];
    const int* edge_index = (const int*)d_in[4];
    const float* eeb = (const float*)d_in[5];
    const float* ln1_s = (const float*)d_in[6];
    const float* ln1_b = (const float*)d_in[7];
    const float* Wq = (const float*)d_in[8];
    const float* bq = (const float*)d_in[9];
    const float* Wk = (const float*)d_in[10];
    const float* bk = (const float*)d_in[11];
    const float* Wv = (const float*)d_in[12];
    const float* bv = (const float*)d_in[13];
    const float* Wo = (const float*)d_in[14];
    const float* bo = (const float*)d_in[15];
    const float* ln2_s = (const float*)d_in[16];
    const float* ln2_b = (const float*)d_in[17];
    const float* W1 = (const float*)d_in[18];
    const float* b1 = (const float*)d_in[19];
    const float* W2 = (const float*)d_in[20];
    const float* b2 = (const float*)d_in[21];
    const float* deg_coef = (const float*)d_in[22];
    const float* We2n = (const float*)d_in[23];
    const float* be2n = (const float*)d_in[24];

    char* ws = (char*)d_ws;
    size_t off = 0;
    auto alloc = [&](size_t bytes) { char* p = ws + off; off += (bytes + 255) & ~(size_t)255; return p; };
    u16* qb = (u16*)alloc((size_t)E_ * 256 * 2);                 // 33.5MB
    unsigned char* kv8 = (unsigned char*)alloc((size_t)E_ * 512); // 33.5MB
    u16* agg = (u16*)alloc((size_t)E_ * 256 * 2);
    unsigned char* ffh8 = (unsigned char*)qb;  // E*1024 bytes = qb+kv8 region exactly
    u16* h1b = (u16*)alloc((size_t)E_ * 256 * 2);  // h1 residual, bf16
    unsigned char* en8 = (unsigned char*)alloc((size_t)E_ * 256);  // fp8 LN1 out (x8)
    unsigned char* h1n8 = en8;  // fp8 LN2 out (x8), reuses en8 after QKV GEMM
    u16* nmsg = (u16*)alloc((size_t)N_ * 256 * 2);
    unsigned char* WqkvT8 = (unsigned char*)alloc(768 * 256);
    float* bqkv = (float*)alloc(768 * 4);
    u16* WoT = (u16*)alloc(256 * 256 * 2);
    unsigned char* W1T8 = (unsigned char*)alloc(1024 * 256);
    unsigned char* W2T8 = (unsigned char*)alloc(256 * 1024);
    u16* We2nT = (u16*)alloc(256 * 256 * 2);
    int* cntE = (int*)alloc((size_t)E_ * 4);
    int* cntN = (int*)alloc((size_t)N_ * 4);
    int* rowStartE = (int*)alloc((size_t)(E_ + 1) * 4);
    int* cursorE = (int*)alloc((size_t)E_ * 4);
    int* csrSrc = (int*)alloc((size_t)M_ * 4);
    float* biasCsr = (float*)alloc((size_t)M_ * 8 * 4);
    float* ldeg = (float*)alloc((size_t)E_ * 4);
    int* rowStartN = (int*)alloc((size_t)(N_ + 1) * 4);
    int* cursorN = (int*)alloc((size_t)N_ * 4);
    int* csrN = (int*)alloc((size_t)2 * E_ * 4);
    int* bsumE = (int*)alloc(256 * 4);
    int* bsumN = (int*)alloc(64 * 4);

    float* out_edge = (float*)d_out;
    float* out_node = out_edge + (size_t)E_ * 256;

    // CSR + weights prep
    ge_zero<<<(E_ + N_) / 256, 256, 0, stream>>>(cntE, E_ + N_);
    ge_convw<<<3331, 256, 0, stream>>>(Wq, Wk, Wv, bq, bk, bv, Wo, W1, W2, We2n,
                                       WqkvT8, bqkv, WoT, W1T8, W2T8, We2nT);
    ge_ln<0, 1><<<E_ / 4, 256, 0, stream>>>(edge_attr, ln1_s, ln1_b, en8);
    ge_count<<<M_ / 256, 256, 0, stream>>>(dst_e, cntE, M_);
    ge_count<<<2 * E_ / 256, 256, 0, stream>>>(edge_index, cntN, 2 * E_);
    ge_bsum<<<E_ / 256, 256, 0, stream>>>(cntE, bsumE, E_);
    ge_bscan<<<1, 256, 0, stream>>>(bsumE, E_ / 256);
    ge_cscan<<<E_ / 256, 256, 0, stream>>>(cntE, bsumE, rowStartE, cursorE, ldeg, E_);
    ge_bsum<<<N_ / 256, 256, 0, stream>>>(cntN, bsumN, N_);
    ge_bscan<<<1, 256, 0, stream>>>(bsumN, N_ / 256);
    ge_cscan<<<N_ / 256, 256, 0, stream>>>(cntN, bsumN, rowStartN, cursorN, nullptr, N_);
    ge_fill_attn<<<M_ / 256, 256, 0, stream>>>(dst_e, src_e, eeb, cursorE, csrSrc, biasCsr, M_);
    ge_fill<<<2 * E_ / 256, 256, 0, stream>>>(edge_index, cursorN, csrN, 2 * E_, E_);

    // QKV projection (fp8 x fp8): en8 @ WqkvT8 -> qb (E,256) bf16 + kv8 (E,512B) fp8
    ge_gemm5f8<<<(E_ / 128) * 6, 256, 0, stream>>>(en8, WqkvT8, E_ / 128, bqkv, qb, kv8);
    // segment attention (fp8 KV gathers) -> agg bf16 (E,256)
    ge_attn<<<E_ / 4, 256, 0, stream>>>(qb, kv8, biasCsr, csrSrc, rowStartE, agg);
    // Wo + residual -> h1 bf16
    ge_gemm<1><<<(E_ / 128) * 2, 256, 0, stream>>>(agg, WoT, 256, E_ / 128, bo,
                                                   edge_attr, nullptr, h1b, 256);
    // LN2 -> h1n8 fp8 (x8 scale), overwrites en8 region (QKV consumer done)
    ge_ln<1, 1><<<E_ / 4, 256, 0, stream>>>(h1b, ln2_s, ln2_b, h1n8);
    // FFN up (fp8 x fp8, nt=4) + gelu -> ffh8 fp8 (E,1024, quad-permuted, x8 scale)
    ge_gemm2f8<<<(E_ / 128) * 8, 256, 0, stream>>>(h1n8, W1T8, E_ / 128, b1, ffh8);
    // FFN down (fp8 x fp8, 256x128, counted-vmcnt, coalesced epilogue) -> edge_out f32
    ge_gemm3f8<<<(E_ / 256) * 2, 256, 0, stream>>>(ffh8, W2T8, E_ / 256, b2,
                                                   h1b, ldeg, deg_coef, out_edge);
    // node aggregation -> nmsg bf16 (N,256)
    ge_nodeagg<<<N_ / 4, 256, 0, stream>>>(out_edge, rowStartN, csrN, nmsg);
    // e2n projection + x residual -> node_out f32 (d_out tail)
    ge_gemm<4><<<(N_ / 128) * 2, 256, 0, stream>>>(nmsg, We2nT, 256, N_ / 128, be2n,
                                                   x, out_node, nullptr, 256);
}

// Round 23
// 365.922 us; speedup vs baseline: 1.0166x; 1.0166x over previous
//
#include <hip/hip_runtime.h>
#include <math.h>

#define E_ 65536
#define N_ 16384
#define M_ 262144

typedef unsigned short u16;
typedef unsigned long long u64;
typedef __attribute__((ext_vector_type(4))) float f32x4;
typedef __attribute__((ext_vector_type(8))) short bf16x8;
typedef __attribute__((ext_vector_type(4))) unsigned short u16x4;
typedef __attribute__((ext_vector_type(2))) unsigned int u32x2;
typedef __attribute__((ext_vector_type(4))) float f4v;

__device__ __forceinline__ float b2f(u16 u) {
    union { unsigned u; float f; } x; x.u = ((unsigned)u) << 16; return x.f;
}
__device__ __forceinline__ u16 f2b(float f) {
    union { float f; unsigned u; } x; x.f = f;
    unsigned r = x.u + 0x7FFFu + ((x.u >> 16) & 1u);
    return (u16)(r >> 16);
}
// sigmoid-form GELU: x * sigmoid(1.702 x). ~1e-2 abs err, fine for bf16/fp8 pipeline.
__device__ __forceinline__ float gelu_f(float x) {
    return x * __builtin_amdgcn_rcpf(1.0f + __expf(-1.702f * x));
}

#define GLDS(gp, lp) __builtin_amdgcn_global_load_lds( \
    (const __attribute__((address_space(1))) void*)(gp), \
    (__attribute__((address_space(3))) void*)(lp), 16, 0, 0)

// ---------------- zero int buffer ----------------
__global__ void ge_zero(int* __restrict__ p, int n) {
    int i = blockIdx.x * 256 + threadIdx.x;
    if (i < n) p[i] = 0;
}

// ---------------- weight convert/transpose/pack ----------------
// WqkvT8 [768][256] fp8 x16 (linear K).  W1T8 [1024][256] fp8 x16 (linear K).
// W2T8 [256][1024] fp8 x16, K-dim QUAD-PERMUTED to match ffh8 layout:
// stored k = base64 + lr*4 + ni  <->  true hidden = base64 + ni*16 + lr.
__global__ void ge_convw(const float* __restrict__ Wq, const float* __restrict__ Wk,
                         const float* __restrict__ Wv, const float* __restrict__ bq,
                         const float* __restrict__ bk, const float* __restrict__ bv,
                         const float* __restrict__ Wo, const float* __restrict__ W1,
                         const float* __restrict__ W2, const float* __restrict__ We2n,
                         unsigned char* __restrict__ WqkvT8, float* __restrict__ bqkv,
                         u16* __restrict__ WoT, unsigned char* __restrict__ W1T8,
                         unsigned char* __restrict__ W2T8, u16* __restrict__ We2nT) {
    long i = (long)blockIdx.x * 256 + threadIdx.x;
    if (i < 196608) {  // WqkvT8 [768][256] fp8, x16
        int n = (int)(i >> 8), k = (int)(i & 255);
        const float* W = (n < 256) ? Wq : ((n < 512) ? Wk : Wv);
        int nn = n & 255;
        unsigned pk = __builtin_amdgcn_cvt_pk_fp8_f32(W[k * 256 + nn] * 16.0f, 0.0f, 0u, false);
        WqkvT8[i] = (unsigned char)(pk & 0xFFu);
        return;
    }
    i -= 196608;
    if (i < 768) { bqkv[i] = (i < 256) ? bq[i] : ((i < 512) ? bk[i - 256] : bv[i - 512]); return; }
    i -= 768;
    if (i < 65536) { int n = (int)(i >> 8), k = (int)(i & 255); WoT[i] = f2b(Wo[k * 256 + n]); return; }
    i -= 65536;
    if (i < 262144) {  // W1T8 [1024][256] fp8, x16 scale, linear K
        int n = (int)(i >> 8), k = (int)(i & 255);
        unsigned pk = __builtin_amdgcn_cvt_pk_fp8_f32(W1[k * 1024 + n] * 16.0f, 0.0f, 0u, false);
        W1T8[i] = (unsigned char)(pk & 0xFFu);
        return;
    }
    i -= 262144;
    if (i < 262144) {  // W2T8 [256][1024] fp8, quad-permuted K, x16 scale
        int n = (int)(i / 1024), k = (int)(i % 1024);
        int k64 = k & 63, base = k - k64;
        int old_k = base + (k64 & 3) * 16 + (k64 >> 2);
        unsigned pk = __builtin_amdgcn_cvt_pk_fp8_f32(W2[old_k * 256 + n] * 16.0f, 0.0f, 0u, false);
        W2T8[i] = (unsigned char)(pk & 0xFFu);
        return;
    }
    i -= 262144;
    if (i < 65536) { int n = (int)(i >> 8), k = (int)(i & 255); We2nT[i] = f2b(We2n[k * 256 + n]); return; }
}

// ---------------- LayerNorm row (D=256); IN: 0=f32,1=bf16; OUT: 0=bf16,1=fp8 x8 ----------------
template <int BF16IN, int FP8OUT>
__global__ __launch_bounds__(256) void ge_ln(const void* __restrict__ in,
                                             const float* __restrict__ s,
                                             const float* __restrict__ b,
                                             void* __restrict__ out) {
    int tid = threadIdx.x, l = tid & 63, w = tid >> 6;
    long r = (long)blockIdx.x * 4 + w;
    float x0, x1, x2, x3;
    if constexpr (BF16IN) {
        u16x4 xv = *(const u16x4*)&((const u16*)in)[r * 256 + 4 * l];
        x0 = b2f(xv[0]); x1 = b2f(xv[1]); x2 = b2f(xv[2]); x3 = b2f(xv[3]);
    } else {
        f4v x = *(const f4v*)&((const float*)in)[r * 256 + 4 * l];
        x0 = x[0]; x1 = x[1]; x2 = x[2]; x3 = x[3];
    }
    float sum = x0 + x1 + x2 + x3;
#pragma unroll
    for (int off = 1; off < 64; off <<= 1) sum += __shfl_xor(sum, off);
    float mean = sum * (1.0f / 256.0f);
    float d0 = x0 - mean, d1 = x1 - mean, d2 = x2 - mean, d3 = x3 - mean;
    float ss = d0 * d0 + d1 * d1 + d2 * d2 + d3 * d3;
#pragma unroll
    for (int off = 1; off < 64; off <<= 1) ss += __shfl_xor(ss, off);
    float rs = rsqrtf(ss * (1.0f / 256.0f) + 1e-5f);
    float y0 = d0 * rs * s[4 * l + 0] + b[4 * l + 0];
    float y1 = d1 * rs * s[4 * l + 1] + b[4 * l + 1];
    float y2 = d2 * rs * s[4 * l + 2] + b[4 * l + 2];
    float y3 = d3 * rs * s[4 * l + 3] + b[4 * l + 3];
    if constexpr (FP8OUT) {
        unsigned pk = __builtin_amdgcn_cvt_pk_fp8_f32(y0 * 8.0f, y1 * 8.0f, 0u, false);
        pk = __builtin_amdgcn_cvt_pk_fp8_f32(y2 * 8.0f, y3 * 8.0f, pk, true);
        *(unsigned*)&((unsigned char*)out)[r * 256 + 4 * l] = pk;
    } else {
        u16x4 o;
        o[0] = f2b(y0); o[1] = f2b(y1); o[2] = f2b(y2); o[3] = f2b(y3);
        *(u16x4*)&((u16*)out)[r * 256 + 4 * l] = o;
    }
}

// ---------------- CSR build: count, hierarchical scan, fill ----------------
__global__ void ge_count(const int* __restrict__ idx, int* __restrict__ cnt, int n) {
    int i = blockIdx.x * 256 + threadIdx.x;
    if (i < n) atomicAdd(&cnt[idx[i]], 1);
}

__global__ __launch_bounds__(256) void ge_bsum(const int* __restrict__ cnt,
                                               int* __restrict__ bsum, int n) {
    int i = blockIdx.x * 256 + threadIdx.x;
    int v = (i < n) ? cnt[i] : 0;
#pragma unroll
    for (int off = 1; off < 64; off <<= 1) v += __shfl_xor(v, off);
    __shared__ int ws_[4];
    int l = threadIdx.x & 63, w = threadIdx.x >> 6;
    if (l == 0) ws_[w] = v;
    __syncthreads();
    if (threadIdx.x == 0) bsum[blockIdx.x] = ws_[0] + ws_[1] + ws_[2] + ws_[3];
}

__global__ __launch_bounds__(256) void ge_bscan(int* __restrict__ bsum, int nb) {
    __shared__ int lds[256];
    int tid = threadIdx.x;
    int v = (tid < nb) ? bsum[tid] : 0;
    lds[tid] = v;
    __syncthreads();
#pragma unroll
    for (int off = 1; off < 256; off <<= 1) {
        int t = (tid >= off) ? lds[tid - off] : 0;
        __syncthreads();
        lds[tid] += t;
        __syncthreads();
    }
    if (tid < nb) bsum[tid] = lds[tid] - v;  // exclusive
}

__global__ __launch_bounds__(256) void ge_cscan(const int* __restrict__ cnt,
                                                const int* __restrict__ bsum,
                                                int* __restrict__ rowStart,
                                                int* __restrict__ cursor,
                                                float* __restrict__ ldeg, int n) {
    __shared__ int lds[256];
    int tid = threadIdx.x;
    int i = blockIdx.x * 256 + tid;
    int c = (i < n) ? cnt[i] : 0;
    lds[tid] = c;
    __syncthreads();
#pragma unroll
    for (int off = 1; off < 256; off <<= 1) {
        int t = (tid >= off) ? lds[tid - off] : 0;
        __syncthreads();
        lds[tid] += t;
        __syncthreads();
    }
    if (i < n) {
        int ex = bsum[blockIdx.x] + lds[tid] - c;
        rowStart[i] = ex;
        cursor[i] = ex;
        if (ldeg) ldeg[i] = log1pf((float)c);
        if (i == n - 1) rowStart[n] = ex + c;
    }
}

__global__ void ge_fill(const int* __restrict__ idx, int* __restrict__ cursor,
                        int* __restrict__ csr, int n, int modE) {
    int i = blockIdx.x * 256 + threadIdx.x;
    if (i < n) {
        int slot = atomicAdd(&cursor[idx[i]], 1);
        csr[slot] = (modE && i >= modE) ? (i - modE) : i;
    }
}

__global__ void ge_fill_attn(const int* __restrict__ dst, const int* __restrict__ src,
                             const float* __restrict__ eeb, int* __restrict__ cursor,
                             int* __restrict__ csrSrc, float* __restrict__ biasCsr, int n) {
    int i = blockIdx.x * 256 + threadIdx.x;
    if (i < n) {
        int slot = atomicAdd(&cursor[dst[i]], 1);
        csrSrc[slot] = src[i];
        f4v b0 = *(const f4v*)&eeb[(size_t)i * 8];
        f4v b1 = *(const f4v*)&eeb[(size_t)i * 8 + 4];
        *(f4v*)&biasCsr[(size_t)slot * 8] = b0;
        *(f4v*)&biasCsr[(size_t)slot * 8 + 4] = b1;
    }
}

// ---------------- GEMM (bf16): 128x128 tile, grouped block order ----------------
// EPI 1: out bf16 = C + bias + res(f32)          (Wo + residual -> h1 bf16)
// EPI 4: out f32  = C + bias + res(f32)          (We2n + x)
template <int EPI>
__global__ __launch_bounds__(256) void ge_gemm(
    const u16* __restrict__ A, const u16* __restrict__ Bt, int K, int nxt,
    const float* __restrict__ bias, const float* __restrict__ res,
    float* __restrict__ outF, u16* __restrict__ outB, int ldOut) {
    __shared__ __align__(16) char smem[32768];
    const int tid = threadIdx.x;
    const int l = tid & 63, w = tid >> 6;
    const int ny = gridDim.x / nxt;
    const int gsz = 64 * ny;
    const int bid = blockIdx.x;
    const int xt = (bid / gsz) * 64 + (bid % gsz) % 64;
    const int yt = (bid % gsz) / 64;
    const int rowBase = xt * 128, colBase = yt * 128;
    const int ar = tid >> 2, aq = tid & 3;
    const int aqs = aq ^ ((ar >> 1) & 3);  // source-side chunk swizzle, phase-uniform
    const u16* Ag = A + (size_t)(rowBase + ar) * K + aqs * 8;
    const u16* Bg = Bt + (size_t)(colBase + ar) * K + aqs * 8;
    const size_t row64 = (size_t)64 * K;

    f32x4 acc[4][4] = {};
    const int lr = l & 15;
    const int ks2 = (((l >> 4) ^ ((l >> 1) & 3)) << 3);  // read-side, f(row)=(row>>1)&3
    const int wr = (w >> 1) * 64, wc = (w & 1) * 64;
    const int nt = K >> 5;

    auto STAGE = [&](int b, int t) {
        const int kk = t * 32;
        char* dA = smem + b * 8192 + w * 1024;
        char* dB = smem + 16384 + b * 8192 + w * 1024;
        GLDS(Ag + kk, dA);
        GLDS(Ag + kk + row64, dA + 4096);
        GLDS(Bg + kk, dB);
        GLDS(Bg + kk + row64, dB + 4096);
    };

    STAGE(0, 0);
    __syncthreads();
    int cur = 0;
    for (int t = 0; t < nt; ++t) {
        if (t + 1 < nt) STAGE(cur ^ 1, t + 1);
        const u16* bufA = (const u16*)(smem + cur * 8192);
        const u16* bufB = (const u16*)(smem + 16384 + cur * 8192);
        bf16x8 af[4], bfr[4];
#pragma unroll
        for (int mi = 0; mi < 4; mi++) af[mi] = *(const bf16x8*)&bufA[(wr + mi * 16 + lr) * 32 + ks2];
#pragma unroll
        for (int ni = 0; ni < 4; ni++) bfr[ni] = *(const bf16x8*)&bufB[(wc + ni * 16 + lr) * 32 + ks2];
#pragma unroll
        for (int mi = 0; mi < 4; mi++)
#pragma unroll
            for (int ni = 0; ni < 4; ni++)
                acc[mi][ni] = __builtin_amdgcn_mfma_f32_16x16x32_bf16(af[mi], bfr[ni], acc[mi][ni], 0, 0, 0);
        if (t + 1 < nt) {
            __syncthreads();
            cur ^= 1;
        }
    }

    const int r0 = (l >> 4) * 4;
#pragma unroll
    for (int mi = 0; mi < 4; mi++) {
#pragma unroll
        for (int ni = 0; ni < 4; ni++) {
#pragma unroll
            for (int r = 0; r < 4; r++) {
                int grow = rowBase + wr + mi * 16 + r0 + r;
                int gcol = colBase + wc + ni * 16 + lr;
                float c = acc[mi][ni][r];
                if constexpr (EPI == 1) {
                    outB[(size_t)grow * ldOut + gcol] =
                        f2b(c + bias[gcol] + res[(size_t)grow * 256 + gcol]);
                } else {
                    outF[(size_t)grow * ldOut + gcol] =
                        c + bias[gcol] + res[(size_t)grow * 256 + gcol];
                }
            }
        }
    }
}

// ---------------- QKV GEMM, fp8 x fp8, 128x128 tile, K=256 (nt=4) ----------------
// A = en8 [E][256] fp8 (LN1 x8), Bt = WqkvT8 [768][256] fp8 (x16). acc/128 + bias.
// Epilogue: LDS transpose -> q [E][256] bf16 + kv8 [E][512 bytes] fp8 x8 interleaved
// (block d: bytes 8d..8d+3 = K[4d..4d+3]*8, bytes 8d+4..8d+7 = V[4d..4d+3]*8).
__global__ __launch_bounds__(256) void ge_gemm5f8(
    const unsigned char* __restrict__ A, const unsigned char* __restrict__ Bt, int nxt,
    const float* __restrict__ bias, u16* __restrict__ outB, unsigned char* __restrict__ outKV8) {
    __shared__ __align__(16) char smem[32768];
    const int tid = threadIdx.x;
    const int l = tid & 63, w = tid >> 6;
    const int ny = gridDim.x / nxt;
    const int gsz = 64 * ny;
    const int bid = blockIdx.x;
    const int xt = (bid / gsz) * 64 + (bid % gsz) % 64;
    const int yt = (bid % gsz) / 64;
    const int rowBase = xt * 128, colBase = yt * 128;
    const int ar = tid >> 2, aq = tid & 3;
    const int aqs = aq ^ ((ar >> 1) & 3);
    const unsigned char* Ag = A + (size_t)(rowBase + ar) * 256 + aqs * 16;
    const unsigned char* Bg = Bt + (size_t)(colBase + ar) * 256 + aqs * 16;
    const size_t row64 = (size_t)64 * 256;

    f32x4 acc[4][4] = {};
    const int lr = l & 15, q = l >> 4;
    const int fx = (l >> 1) & 3;
    const int wr = (w >> 1) * 64, wc = (w & 1) * 64;

    auto STAGE = [&](int b, int t) {
        const size_t kk = (size_t)t * 64;
        char* dA = smem + b * 8192 + w * 1024;
        char* dB = smem + 16384 + b * 8192 + w * 1024;
        GLDS(Ag + kk, dA);
        GLDS(Ag + kk + row64, dA + 4096);
        GLDS(Bg + kk, dB);
        GLDS(Bg + kk + row64, dB + 4096);
    };

    STAGE(0, 0);
    __syncthreads();
    int cur = 0;
    for (int t = 0; t < 4; ++t) {
        if (t + 1 < 4) STAGE(cur ^ 1, t + 1);
        const unsigned char* bufA = (const unsigned char*)(smem + cur * 8192);
        const unsigned char* bufB = (const unsigned char*)(smem + 16384 + cur * 8192);
#pragma unroll
        for (int s = 0; s < 2; ++s) {
            long long af[4], bf[4];
#pragma unroll
            for (int mi = 0; mi < 4; mi++) {
                int row = wr + mi * 16 + lr;
                af[mi] = *(const long long*)&bufA[row * 64 + ((2 * s + (q >> 1)) ^ fx) * 16 + (q & 1) * 8];
            }
#pragma unroll
            for (int ni = 0; ni < 4; ni++) {
                int col = wc + ni * 16 + lr;
                bf[ni] = *(const long long*)&bufB[col * 64 + ((2 * s + (q >> 1)) ^ fx) * 16 + (q & 1) * 8];
            }
#pragma unroll
            for (int mi = 0; mi < 4; mi++)
#pragma unroll
                for (int ni = 0; ni < 4; ni++)
                    acc[mi][ni] = __builtin_amdgcn_mfma_f32_16x16x32_fp8_fp8(af[mi], bf[ni], acc[mi][ni], 0, 0, 0);
        }
        if (t + 1 < 4) {
            __syncthreads();
            cur ^= 1;
        }
    }

    const int r0 = q * 4;
    // LDS transpose epilogue: acc/128 + bias -> bf16 staging, then q bf16 / kv fp8 stores
    __syncthreads();
    u16* ep = (u16*)smem;  // [128][128]
#pragma unroll
    for (int mi = 0; mi < 4; mi++) {
#pragma unroll
        for (int ni = 0; ni < 4; ni++) {
#pragma unroll
            for (int r = 0; r < 4; r++) {
                int rl = wr + mi * 16 + r0 + r;
                int cl = wc + ni * 16 + lr;
                float c = acc[mi][ni][r] * 0.0078125f + bias[colBase + cl];
                ep[rl * 128 + (cl ^ (((rl >> 2) & 3) << 4))] = f2b(c);
            }
        }
    }
    __syncthreads();
#pragma unroll
    for (int j = 0; j < 8; j++) {
        int lin = tid + j * 256;
        int row = lin >> 4, ch = lin & 15;
        int grow = rowBase + row;
        bf16x8 v = *(const bf16x8*)&ep[row * 128 + ((ch * 8) ^ (((row >> 2) & 3) << 4))];
        int gcol0 = colBase + ch * 8;
        if (gcol0 < 256) {
            *(bf16x8*)&outB[(size_t)grow * 256 + gcol0] = v;
        } else {
            float f0 = b2f((u16)v[0]) * 8.0f, f1 = b2f((u16)v[1]) * 8.0f;
            float f2 = b2f((u16)v[2]) * 8.0f, f3 = b2f((u16)v[3]) * 8.0f;
            float f4 = b2f((u16)v[4]) * 8.0f, f5 = b2f((u16)v[5]) * 8.0f;
            float f6 = b2f((u16)v[6]) * 8.0f, f7 = b2f((u16)v[7]) * 8.0f;
            unsigned pk0 = __builtin_amdgcn_cvt_pk_fp8_f32(f0, f1, 0u, false);
            pk0 = __builtin_amdgcn_cvt_pk_fp8_f32(f2, f3, pk0, true);
            unsigned pk1 = __builtin_amdgcn_cvt_pk_fp8_f32(f4, f5, 0u, false);
            pk1 = __builtin_amdgcn_cvt_pk_fp8_f32(f6, f7, pk1, true);
            if (gcol0 < 512) {
                int d0 = (gcol0 - 256) >> 2;  // even
                size_t base = (size_t)grow * 512 + 8 * d0;
                *(unsigned*)&outKV8[base] = pk0;
                *(unsigned*)&outKV8[base + 8] = pk1;
            } else {
                int d0 = (gcol0 - 512) >> 2;  // even
                size_t base = (size_t)grow * 512 + 8 * d0 + 4;
                *(unsigned*)&outKV8[base] = pk0;
                *(unsigned*)&outKV8[base + 8] = pk1;
            }
        }
    }
}

// ---------------- FFN-up GEMM, fp8 x fp8, 128x128 tile, K=256 (nt=4, R16-proven) ------
__global__ __launch_bounds__(256) void ge_gemm2f8(
    const unsigned char* __restrict__ A, const unsigned char* __restrict__ Bt, int nxt,
    const float* __restrict__ bias, unsigned char* __restrict__ out8) {
    __shared__ __align__(16) char smem[32768];
    const int tid = threadIdx.x;
    const int l = tid & 63, w = tid >> 6;
    const int ny = gridDim.x / nxt;
    const int gsz = 64 * ny;
    const int bid = blockIdx.x;
    const int xt = (bid / gsz) * 64 + (bid % gsz) % 64;
    const int yt = (bid % gsz) / 64;
    const int rowBase = xt * 128, colBase = yt * 128;
    const int ar = tid >> 2, aq = tid & 3;
    const int aqs = aq ^ ((ar >> 1) & 3);
    const unsigned char* Ag = A + (size_t)(rowBase + ar) * 256 + aqs * 16;
    const unsigned char* Bg = Bt + (size_t)(colBase + ar) * 256 + aqs * 16;
    const size_t row64 = (size_t)64 * 256;

    f32x4 acc[4][4] = {};
    const int lr = l & 15, q = l >> 4;
    const int fx = (l >> 1) & 3;
    const int wr = (w >> 1) * 64, wc = (w & 1) * 64;

    auto STAGE = [&](int b, int t) {
        const size_t kk = (size_t)t * 64;
        char* dA = smem + b * 8192 + w * 1024;
        char* dB = smem + 16384 + b * 8192 + w * 1024;
        GLDS(Ag + kk, dA);
        GLDS(Ag + kk + row64, dA + 4096);
        GLDS(Bg + kk, dB);
        GLDS(Bg + kk + row64, dB + 4096);
    };

    STAGE(0, 0);
    __syncthreads();
    int cur = 0;
    for (int t = 0; t < 4; ++t) {
        if (t + 1 < 4) STAGE(cur ^ 1, t + 1);
        const unsigned char* bufA = (const unsigned char*)(smem + cur * 8192);
        const unsigned char* bufB = (const unsigned char*)(smem + 16384 + cur * 8192);
#pragma unroll
        for (int s = 0; s < 2; ++s) {
            long long af[4], bf[4];
#pragma unroll
            for (int mi = 0; mi < 4; mi++) {
                int row = wr + mi * 16 + lr;
                af[mi] = *(const long long*)&bufA[row * 64 + ((2 * s + (q >> 1)) ^ fx) * 16 + (q & 1) * 8];
            }
#pragma unroll
            for (int ni = 0; ni < 4; ni++) {
                int col = wc + ni * 16 + lr;
                bf[ni] = *(const long long*)&bufB[col * 64 + ((2 * s + (q >> 1)) ^ fx) * 16 + (q & 1) * 8];
            }
#pragma unroll
            for (int mi = 0; mi < 4; mi++)
#pragma unroll
                for (int ni = 0; ni < 4; ni++)
                    acc[mi][ni] = __builtin_amdgcn_mfma_f32_16x16x32_fp8_fp8(af[mi], bf[ni], acc[mi][ni], 0, 0, 0);
        }
        if (t + 1 < 4) {
            __syncthreads();
            cur ^= 1;
        }
    }

    const int r0 = q * 4;
    float bv[4];
#pragma unroll
    for (int ni = 0; ni < 4; ni++) bv[ni] = bias[colBase + wc + ni * 16 + lr];
#pragma unroll
    for (int mi = 0; mi < 4; mi++) {
#pragma unroll
        for (int r = 0; r < 4; r++) {
            int grow = rowBase + wr + mi * 16 + r0 + r;
            float v0 = gelu_f(acc[mi][0][r] * 0.0078125f + bv[0]) * 8.0f;
            float v1 = gelu_f(acc[mi][1][r] * 0.0078125f + bv[1]) * 8.0f;
            float v2 = gelu_f(acc[mi][2][r] * 0.0078125f + bv[2]) * 8.0f;
            float v3 = gelu_f(acc[mi][3][r] * 0.0078125f + bv[3]) * 8.0f;
            unsigned pk = __builtin_amdgcn_cvt_pk_fp8_f32(v0, v1, 0u, false);
            pk = __builtin_amdgcn_cvt_pk_fp8_f32(v2, v3, pk, true);
            *(unsigned*)&out8[(size_t)grow * 1024 + colBase + wc + lr * 4] = pk;
        }
    }
}

// ---------------- FFN-down GEMM, fp8 x fp8, 256x128 tile (R15-proven) ----------------
__global__ __launch_bounds__(256) void ge_gemm3f8(
    const unsigned char* __restrict__ A, const unsigned char* __restrict__ Bt, int nxt,
    const float* __restrict__ bias, const u16* __restrict__ resB,
    const float* __restrict__ ldeg, const float* __restrict__ dcoef,
    float* __restrict__ outF) {
    __shared__ __align__(16) char smem[49152];
    const int tid = threadIdx.x;
    const int l = tid & 63, w = tid >> 6;
    const int ny = gridDim.x / nxt;
    const int gsz = 64 * ny;
    const int bid = blockIdx.x;
    const int xt = (bid / gsz) * 64 + (bid % gsz) % 64;
    const int yt = (bid % gsz) / 64;
    const int rowBase = xt * 256, colBase = yt * 128;
    const int ar = tid >> 2, aq = tid & 3;
    const int aqs = aq ^ ((ar >> 1) & 3);
    const unsigned char* Ag = A + (size_t)(rowBase + ar) * 1024 + aqs * 16;
    const unsigned char* Bg = Bt + (size_t)(colBase + ar) * 1024 + aqs * 16;
    const size_t row64 = (size_t)64 * 1024;

    f32x4 acc[8][4] = {};
    const int lr = l & 15, q = l >> 4;
    const int fx = (l >> 1) & 3;
    const int wr = (w >> 1) * 128, wc = (w & 1) * 64;

    auto STAGE = [&](int b, int t) {
        const size_t kk = (size_t)t * 64;
        char* dA = smem + b * 16384 + w * 1024;
        char* dB = smem + 32768 + b * 8192 + w * 1024;
        GLDS(Ag + kk, dA);
        GLDS(Ag + kk + row64, dA + 4096);
        GLDS(Ag + kk + 2 * row64, dA + 8192);
        GLDS(Ag + kk + 3 * row64, dA + 12288);
        GLDS(Bg + kk, dB);
        GLDS(Bg + kk + row64, dB + 4096);
    };

    STAGE(0, 0);
    __syncthreads();
    int cur = 0;
    for (int t = 0; t < 16; ++t) {
        if (t + 1 < 16) STAGE(cur ^ 1, t + 1);
        const unsigned char* bufA = (const unsigned char*)(smem + cur * 16384);
        const unsigned char* bufB = (const unsigned char*)(smem + 32768 + cur * 8192);
#pragma unroll
        for (int s = 0; s < 2; ++s) {
            long long af[8], bf[4];
#pragma unroll
            for (int mi = 0; mi < 8; mi++) {
                int row = wr + mi * 16 + lr;
                af[mi] = *(const long long*)&bufA[row * 64 + ((2 * s + (q >> 1)) ^ fx) * 16 + (q & 1) * 8];
            }
#pragma unroll
            for (int ni = 0; ni < 4; ni++) {
                int col = wc + ni * 16 + lr;
                bf[ni] = *(const long long*)&bufB[col * 64 + ((2 * s + (q >> 1)) ^ fx) * 16 + (q & 1) * 8];
            }
#pragma unroll
            for (int mi = 0; mi < 8; mi++)
#pragma unroll
                for (int ni = 0; ni < 4; ni++)
                    acc[mi][ni] = __builtin_amdgcn_mfma_f32_16x16x32_fp8_fp8(af[mi], bf[ni], acc[mi][ni], 0, 0, 0);
        }
        if (t + 1 < 16) {
            __syncthreads();
            cur ^= 1;
        }
    }

    const int r0 = q * 4;
#pragma unroll
    for (int mi = 0; mi < 8; mi++) {
#pragma unroll
        for (int ni = 0; ni < 4; ni++) {
#pragma unroll
            for (int r = 0; r < 4; r++) {
                int grow = rowBase + wr + mi * 16 + r0 + r;
                int gcol = colBase + wc + ni * 16 + lr;
                float t2 = acc[mi][ni][r] * 0.0078125f + bias[gcol] +
                           b2f(resB[(size_t)grow * 256 + gcol]);
                outF[(size_t)grow * 256 + gcol] =
                    t2 * (dcoef[2 * gcol] + ldeg[grow] * dcoef[2 * gcol + 1]);
            }
        }
    }
}

// ---------------- per-dst-segment attention: fp8 KV gathers, single-pass softmax ------
// kv8 row: block d: bytes 8d..8d+3 = K[4d..4d+3]*8 fp8, bytes 8d+4..8d+7 = V[4d..4d+3]*8.
// Lane l reads 8 bytes; scales folded: logit = p*(scale/8)+bias, out = a*(1/8)/sum.
__global__ __launch_bounds__(256) void ge_attn(const u16* __restrict__ qb,
                                               const unsigned char* __restrict__ kv8,
                                               const float* __restrict__ biasCsr,
                                               const int* __restrict__ csrSrc,
                                               const int* __restrict__ rowStart,
                                               u16* __restrict__ agg) {
    int tid = threadIdx.x, l = tid & 63, w = tid >> 6;
    int e = blockIdx.x * 4 + w;
    int g = l >> 3;
    const float scale8 = 0.022097086912079608f;  // 32^-0.5 / 8
    u16x4 qv = *(const u16x4*)&qb[(size_t)e * 256 + 4 * l];
    float q0 = b2f(qv[0]), q1 = b2f(qv[1]), q2 = b2f(qv[2]), q3 = b2f(qv[3]);
    int s0 = rowStart[e], s1 = rowStart[e + 1];

    float sum = 0.0f, a0 = 0.0f, a1 = 0.0f, a2 = 0.0f, a3 = 0.0f;
    if (s0 < s1) {
        int sc = csrSrc[s0];
        u64 kvc = *(const u64*)&kv8[(size_t)sc * 512 + 8 * l];
        float bc = biasCsr[(size_t)s0 * 8 + g];
        for (int i = s0; i < s1; i++) {
            int inx = (i + 1 < s1) ? (i + 1) : i;
            int sn = csrSrc[inx];
            u64 kvn = *(const u64*)&kv8[(size_t)sn * 512 + 8 * l];
            float bn = biasCsr[(size_t)inx * 8 + g];
            unsigned klo = (unsigned)kvc, vhi = (unsigned)(kvc >> 32);
            float p = q0 * __builtin_amdgcn_cvt_f32_fp8(klo, 0) +
                      q1 * __builtin_amdgcn_cvt_f32_fp8(klo, 1) +
                      q2 * __builtin_amdgcn_cvt_f32_fp8(klo, 2) +
                      q3 * __builtin_amdgcn_cvt_f32_fp8(klo, 3);
            p += __shfl_xor(p, 1);
            p += __shfl_xor(p, 2);
            p += __shfl_xor(p, 4);
            float ex = __expf(p * scale8 + bc);  // logits bounded, no max pass needed
            sum += ex;
            a0 += ex * __builtin_amdgcn_cvt_f32_fp8(vhi, 0);
            a1 += ex * __builtin_amdgcn_cvt_f32_fp8(vhi, 1);
            a2 += ex * __builtin_amdgcn_cvt_f32_fp8(vhi, 2);
            a3 += ex * __builtin_amdgcn_cvt_f32_fp8(vhi, 3);
            kvc = kvn;
            bc = bn;
        }
    }
    float inv = 0.125f / (sum + 1e-16f);
    u16x4 o;
    o[0] = f2b(a0 * inv);
    o[1] = f2b(a1 * inv);
    o[2] = f2b(a2 * inv);
    o[3] = f2b(a3 * inv);
    *(u16x4*)&agg[(size_t)e * 256 + 4 * l] = o;
}

// ---------------- node aggregation: sum edge_out rows per node -> bf16 ----------------
__global__ __launch_bounds__(256) void ge_nodeagg(const float* __restrict__ edge_out,
                                                  const int* __restrict__ rowStart,
                                                  const int* __restrict__ csr,
                                                  u16* __restrict__ nmsg) {
    int tid = threadIdx.x, l = tid & 63, w = tid >> 6;
    int n = blockIdx.x * 4 + w;
    int s0 = rowStart[n], s1 = rowStart[n + 1];
    float a0 = 0.0f, a1 = 0.0f, a2 = 0.0f, a3 = 0.0f;
    for (int i = s0; i < s1; i++) {
        int e = csr[i];
        f4v v = *(const f4v*)&edge_out[(size_t)e * 256 + 4 * l];
        a0 += v[0]; a1 += v[1]; a2 += v[2]; a3 += v[3];
    }
    u16x4 o;
    o[0] = f2b(a0); o[1] = f2b(a1); o[2] = f2b(a2); o[3] = f2b(a3);
    *(u16x4*)&nmsg[(size_t)n * 256 + 4 * l] = o;
}

extern "C" void kernel_launch(void* const* d_in, const int* in_sizes, int n_in,
                              void* d_out, int out_size, void* d_ws, size_t ws_size,
                              hipStream_t stream) {
    (void)in_sizes; (void)n_in; (void)out_size; (void)ws_size;
    const float* edge_attr = (const float*)d_in[0];
    const float* x = (const float*)d_in[1];
    const int* src_e = (const int*)d_in[2];
    const int* dst_e = (const int*)d_in[3];
    const int* edge_index = (const int*)d_in[4];
    const float* eeb = (const float*)d_in[5];
    const float* ln1_s = (const float*)d_in[6];
    const float* ln1_b = (const float*)d_in[7];
    const float* Wq = (const float*)d_in[8];
    const float* bq = (const float*)d_in[9];
    const float* Wk = (const float*)d_in[10];
    const float* bk = (const float*)d_in[11];
    const float* Wv = (const float*)d_in[12];
    const float* bv = (const float*)d_in[13];
    const float* Wo = (const float*)d_in[14];
    const float* bo = (const float*)d_in[15];
    const float* ln2_s = (const float*)d_in[16];
    const float* ln2_b = (const float*)d_in[17];
    const float* W1 = (const float*)d_in[18];
    const float* b1 = (const float*)d_in[19];
    const float* W2 = (const float*)d_in[20];
    const float* b2 = (const float*)d_in[21];
    const float* deg_coef = (const float*)d_in[22];
    const float* We2n = (const float*)d_in[23];
    const float* be2n = (const float*)d_in[24];

    char* ws = (char*)d_ws;
    size_t off = 0;
    auto alloc = [&](size_t bytes) { char* p = ws + off; off += (bytes + 255) & ~(size_t)255; return p; };
    u16* qb = (u16*)alloc((size_t)E_ * 256 * 2);                 // 33.5MB
    unsigned char* kv8 = (unsigned char*)alloc((size_t)E_ * 512); // 33.5MB
    u16* agg = (u16*)alloc((size_t)E_ * 256 * 2);
    unsigned char* ffh8 = (unsigned char*)qb;  // E*1024 bytes = qb+kv8 region exactly
    u16* h1b = (u16*)alloc((size_t)E_ * 256 * 2);  // h1 residual, bf16
    unsigned char* en8 = (unsigned char*)alloc((size_t)E_ * 256);  // fp8 LN1 out (x8)
    unsigned char* h1n8 = en8;  // fp8 LN2 out (x8), reuses en8 after QKV GEMM
    u16* nmsg = (u16*)alloc((size_t)N_ * 256 * 2);
    unsigned char* WqkvT8 = (unsigned char*)alloc(768 * 256);
    float* bqkv = (float*)alloc(768 * 4);
    u16* WoT = (u16*)alloc(256 * 256 * 2);
    unsigned char* W1T8 = (unsigned char*)alloc(1024 * 256);
    unsigned char* W2T8 = (unsigned char*)alloc(256 * 1024);
    u16* We2nT = (u16*)alloc(256 * 256 * 2);
    int* cntE = (int*)alloc((size_t)E_ * 4);
    int* cntN = (int*)alloc((size_t)N_ * 4);
    int* rowStartE = (int*)alloc((size_t)(E_ + 1) * 4);
    int* cursorE = (int*)alloc((size_t)E_ * 4);
    int* csrSrc = (int*)alloc((size_t)M_ * 4);
    float* biasCsr = (float*)alloc((size_t)M_ * 8 * 4);
    float* ldeg = (float*)alloc((size_t)E_ * 4);
    int* rowStartN = (int*)alloc((size_t)(N_ + 1) * 4);
    int* cursorN = (int*)alloc((size_t)N_ * 4);
    int* csrN = (int*)alloc((size_t)2 * E_ * 4);
    int* bsumE = (int*)alloc(256 * 4);
    int* bsumN = (int*)alloc(64 * 4);

    float* out_edge = (float*)d_out;
    float* out_node = out_edge + (size_t)E_ * 256;

    // CSR + weights prep
    ge_zero<<<(E_ + N_) / 256, 256, 0, stream>>>(cntE, E_ + N_);
    ge_convw<<<3331, 256, 0, stream>>>(Wq, Wk, Wv, bq, bk, bv, Wo, W1, W2, We2n,
                                       WqkvT8, bqkv, WoT, W1T8, W2T8, We2nT);
    ge_ln<0, 1><<<E_ / 4, 256, 0, stream>>>(edge_attr, ln1_s, ln1_b, en8);
    ge_count<<<M_ / 256, 256, 0, stream>>>(dst_e, cntE, M_);
    ge_count<<<2 * E_ / 256, 256, 0, stream>>>(edge_index, cntN, 2 * E_);
    ge_bsum<<<E_ / 256, 256, 0, stream>>>(cntE, bsumE, E_);
    ge_bscan<<<1, 256, 0, stream>>>(bsumE, E_ / 256);
    ge_cscan<<<E_ / 256, 256, 0, stream>>>(cntE, bsumE, rowStartE, cursorE, ldeg, E_);
    ge_bsum<<<N_ / 256, 256, 0, stream>>>(cntN, bsumN, N_);
    ge_bscan<<<1, 256, 0, stream>>>(bsumN, N_ / 256);
    ge_cscan<<<N_ / 256, 256, 0, stream>>>(cntN, bsumN, rowStartN, cursorN, nullptr, N_);
    ge_fill_attn<<<M_ / 256, 256, 0, stream>>>(dst_e, src_e, eeb, cursorE, csrSrc, biasCsr, M_);
    ge_fill<<<2 * E_ / 256, 256, 0, stream>>>(edge_index, cursorN, csrN, 2 * E_, E_);

    // QKV projection (fp8 x fp8): en8 @ WqkvT8 -> qb (E,256) bf16 + kv8 (E,512B) fp8
    ge_gemm5f8<<<(E_ / 128) * 6, 256, 0, stream>>>(en8, WqkvT8, E_ / 128, bqkv, qb, kv8);
    // segment attention (fp8 KV gathers) -> agg bf16 (E,256)
    ge_attn<<<E_ / 4, 256, 0, stream>>>(qb, kv8, biasCsr, csrSrc, rowStartE, agg);
    // Wo + residual -> h1 bf16
    ge_gemm<1><<<(E_ / 128) * 2, 256, 0, stream>>>(agg, WoT, 256, E_ / 128, bo,
                                                   edge_attr, nullptr, h1b, 256);
    // LN2 -> h1n8 fp8 (x8 scale), overwrites en8 region (QKV consumer done)
    ge_ln<1, 1><<<E_ / 4, 256, 0, stream>>>(h1b, ln2_s, ln2_b, h1n8);
    // FFN up (fp8 x fp8, nt=4) + gelu -> ffh8 fp8 (E,1024, quad-permuted, x8 scale)
    ge_gemm2f8<<<(E_ / 128) * 8, 256, 0, stream>>>(h1n8, W1T8, E_ / 128, b1, ffh8);
    // FFN down (fp8 x fp8, 256x128 tile) + residual + degree scaling -> edge_out f32
    ge_gemm3f8<<<(E_ / 256) * 2, 256, 0, stream>>>(ffh8, W2T8, E_ / 256, b2,
                                                   h1b, ldeg, deg_coef, out_edge);
    // node aggregation -> nmsg bf16 (N,256)
    ge_nodeagg<<<N_ / 4, 256, 0, stream>>>(out_edge, rowStartN, csrN, nmsg);
    // e2n projection + x residual -> node_out f32 (d_out tail)
    ge_gemm<4><<<(N_ / 128) * 2, 256, 0, stream>>>(nmsg, We2nT, 256, N_ / 128, be2n,
                                                   x, out_node, nullptr, 256);
}